// Round 1
// baseline (884.003 us; speedup 1.0000x reference)
//
#include <hip/hip_runtime.h>
#include <hip/hip_bf16.h>
#include <stdint.h>

#define NA 500000
#define NB 500000
#define EE 1000000

__device__ __forceinline__ uint32_t f2bf(float f) {
    uint32_t b = __builtin_bit_cast(uint32_t, f);
    return (b + 0x7FFFu + ((b >> 16) & 1u)) >> 16;  // RNE
}
__device__ __forceinline__ float bf2f(uint16_t u) {
    uint32_t b = ((uint32_t)u) << 16;
    return __builtin_bit_cast(float, b);
}

// ---- layer-1 scalar aggregation: agg[dst] += x[src] ----
__global__ __launch_bounds__(256) void edge_scalar_agg(
    const int* __restrict__ ei, const float* __restrict__ x,
    float* __restrict__ agg) {
    int e = blockIdx.x * 256 + threadIdx.x;
    if (e >= EE) return;
    int s = ei[e];
    int d = ei[EE + e];
    atomicAdd(&agg[d], x[s]);
}

// ---- a-nodes: h = relu(rank-1 stuff); ta0=h@Wrel2[0], ta2=h@Wrel2[2] (bf16);
//      outa = h@(Wroot2[1]+Wroot2[2]) + b2[1]+b2[2] ----
__global__ __launch_bounds__(256) void node_a_kernel(
    const float* __restrict__ xa,
    const float* __restrict__ s_ba, const float* __restrict__ s_aa,
    const float* __restrict__ Wrel1, const float* __restrict__ Wroot1,
    const float* __restrict__ b1,
    const float* __restrict__ Wrel2, const float* __restrict__ Wroot2,
    const float* __restrict__ b2,
    uint16_t* __restrict__ ta0, uint16_t* __restrict__ ta2,
    float* __restrict__ outa) {
    __shared__ float uS[64], vS[64], wS[64], cS[64], bbS[32];
    __shared__ float W0[2048], W2[2048], WrS[2048];
    const int t = threadIdx.x;
    if (t < 64) {
        uS[t] = Wrel1[64 + t];                      // W_rel1[1][0][t]
        vS[t] = Wrel1[128 + t];                     // W_rel1[2][0][t]
        wS[t] = Wroot1[64 + t] + Wroot1[128 + t];
        cS[t] = b1[64 + t] + b1[128 + t];
    }
    if (t >= 64 && t < 96) bbS[t - 64] = b2[32 + (t - 64)] + b2[64 + (t - 64)];
    for (int i = t; i < 2048; i += 256) {
        W0[i]  = Wrel2[i];                          // W_rel2[0]
        W2[i]  = Wrel2[4096 + i];                   // W_rel2[2]
        WrS[i] = Wroot2[2048 + i] + Wroot2[4096 + i];
    }
    __syncthreads();
    const int n = blockIdx.x * 256 + t;
    if (n >= NA) return;
    const float sba = s_ba[n], saa = s_aa[n], x = xa[n];
    float h[64];
#pragma unroll
    for (int j = 0; j < 64; ++j)
        h[j] = fmaxf(fmaf(sba, uS[j], fmaf(saa, vS[j], fmaf(x, wS[j], cS[j]))), 0.f);

    float acc[32];
    // ta0
#pragma unroll
    for (int o = 0; o < 32; ++o) acc[o] = 0.f;
#pragma unroll 8
    for (int j = 0; j < 64; ++j) {
        const float hj = h[j];
        const float4* w4 = (const float4*)(&W0[j * 32]);
#pragma unroll
        for (int q = 0; q < 8; ++q) {
            float4 wv = w4[q];
            acc[q * 4 + 0] = fmaf(hj, wv.x, acc[q * 4 + 0]);
            acc[q * 4 + 1] = fmaf(hj, wv.y, acc[q * 4 + 1]);
            acc[q * 4 + 2] = fmaf(hj, wv.z, acc[q * 4 + 2]);
            acc[q * 4 + 3] = fmaf(hj, wv.w, acc[q * 4 + 3]);
        }
    }
    {
        uint32_t pk[16];
#pragma unroll
        for (int k = 0; k < 16; ++k)
            pk[k] = f2bf(acc[2 * k]) | (f2bf(acc[2 * k + 1]) << 16);
        uint4* p = (uint4*)(ta0 + (size_t)n * 32);
#pragma unroll
        for (int q = 0; q < 4; ++q)
            p[q] = make_uint4(pk[4 * q], pk[4 * q + 1], pk[4 * q + 2], pk[4 * q + 3]);
    }
    // ta2
#pragma unroll
    for (int o = 0; o < 32; ++o) acc[o] = 0.f;
#pragma unroll 8
    for (int j = 0; j < 64; ++j) {
        const float hj = h[j];
        const float4* w4 = (const float4*)(&W2[j * 32]);
#pragma unroll
        for (int q = 0; q < 8; ++q) {
            float4 wv = w4[q];
            acc[q * 4 + 0] = fmaf(hj, wv.x, acc[q * 4 + 0]);
            acc[q * 4 + 1] = fmaf(hj, wv.y, acc[q * 4 + 1]);
            acc[q * 4 + 2] = fmaf(hj, wv.z, acc[q * 4 + 2]);
            acc[q * 4 + 3] = fmaf(hj, wv.w, acc[q * 4 + 3]);
        }
    }
    {
        uint32_t pk[16];
#pragma unroll
        for (int k = 0; k < 16; ++k)
            pk[k] = f2bf(acc[2 * k]) | (f2bf(acc[2 * k + 1]) << 16);
        uint4* p = (uint4*)(ta2 + (size_t)n * 32);
#pragma unroll
        for (int q = 0; q < 4; ++q)
            p[q] = make_uint4(pk[4 * q], pk[4 * q + 1], pk[4 * q + 2], pk[4 * q + 3]);
    }
    // outa (root part + bias)
#pragma unroll
    for (int o = 0; o < 32; ++o) acc[o] = bbS[o];
#pragma unroll 8
    for (int j = 0; j < 64; ++j) {
        const float hj = h[j];
        const float4* w4 = (const float4*)(&WrS[j * 32]);
#pragma unroll
        for (int q = 0; q < 8; ++q) {
            float4 wv = w4[q];
            acc[q * 4 + 0] = fmaf(hj, wv.x, acc[q * 4 + 0]);
            acc[q * 4 + 1] = fmaf(hj, wv.y, acc[q * 4 + 1]);
            acc[q * 4 + 2] = fmaf(hj, wv.z, acc[q * 4 + 2]);
            acc[q * 4 + 3] = fmaf(hj, wv.w, acc[q * 4 + 3]);
        }
    }
    {
        float4* p = (float4*)(outa + (size_t)n * 32);
#pragma unroll
        for (int q = 0; q < 8; ++q)
            p[q] = make_float4(acc[4 * q], acc[4 * q + 1], acc[4 * q + 2], acc[4 * q + 3]);
    }
}

// ---- b-nodes: hb = relu(...); tb1 = hb@Wrel2[1] (bf16); outb = hb@Wroot2[0]+b2[0] ----
__global__ __launch_bounds__(256) void node_b_kernel(
    const float* __restrict__ xb, const float* __restrict__ s_ab,
    const float* __restrict__ Wrel1, const float* __restrict__ Wroot1,
    const float* __restrict__ b1,
    const float* __restrict__ Wrel2, const float* __restrict__ Wroot2,
    const float* __restrict__ b2,
    uint16_t* __restrict__ tb1, float* __restrict__ outb) {
    __shared__ float uS[64], wS[64], cS[64], bbS[32];
    __shared__ float W1[2048], WrS[2048];
    const int t = threadIdx.x;
    if (t < 64) {
        uS[t] = Wrel1[t];       // W_rel1[0][0][t]
        wS[t] = Wroot1[t];
        cS[t] = b1[t];
    }
    if (t >= 64 && t < 96) bbS[t - 64] = b2[t - 64];
    for (int i = t; i < 2048; i += 256) {
        W1[i]  = Wrel2[2048 + i];   // W_rel2[1]
        WrS[i] = Wroot2[i];         // W_root2[0]
    }
    __syncthreads();
    const int n = blockIdx.x * 256 + t;
    if (n >= NB) return;
    const float sab = s_ab[n], x = xb[n];
    float h[64];
#pragma unroll
    for (int j = 0; j < 64; ++j)
        h[j] = fmaxf(fmaf(sab, uS[j], fmaf(x, wS[j], cS[j])), 0.f);

    float acc[32];
#pragma unroll
    for (int o = 0; o < 32; ++o) acc[o] = 0.f;
#pragma unroll 8
    for (int j = 0; j < 64; ++j) {
        const float hj = h[j];
        const float4* w4 = (const float4*)(&W1[j * 32]);
#pragma unroll
        for (int q = 0; q < 8; ++q) {
            float4 wv = w4[q];
            acc[q * 4 + 0] = fmaf(hj, wv.x, acc[q * 4 + 0]);
            acc[q * 4 + 1] = fmaf(hj, wv.y, acc[q * 4 + 1]);
            acc[q * 4 + 2] = fmaf(hj, wv.z, acc[q * 4 + 2]);
            acc[q * 4 + 3] = fmaf(hj, wv.w, acc[q * 4 + 3]);
        }
    }
    {
        uint32_t pk[16];
#pragma unroll
        for (int k = 0; k < 16; ++k)
            pk[k] = f2bf(acc[2 * k]) | (f2bf(acc[2 * k + 1]) << 16);
        uint4* p = (uint4*)(tb1 + (size_t)n * 32);
#pragma unroll
        for (int q = 0; q < 4; ++q)
            p[q] = make_uint4(pk[4 * q], pk[4 * q + 1], pk[4 * q + 2], pk[4 * q + 3]);
    }
#pragma unroll
    for (int o = 0; o < 32; ++o) acc[o] = bbS[o];
#pragma unroll 8
    for (int j = 0; j < 64; ++j) {
        const float hj = h[j];
        const float4* w4 = (const float4*)(&WrS[j * 32]);
#pragma unroll
        for (int q = 0; q < 8; ++q) {
            float4 wv = w4[q];
            acc[q * 4 + 0] = fmaf(hj, wv.x, acc[q * 4 + 0]);
            acc[q * 4 + 1] = fmaf(hj, wv.y, acc[q * 4 + 1]);
            acc[q * 4 + 2] = fmaf(hj, wv.z, acc[q * 4 + 2]);
            acc[q * 4 + 3] = fmaf(hj, wv.w, acc[q * 4 + 3]);
        }
    }
    {
        float4* p = (float4*)(outb + (size_t)n * 32);
#pragma unroll
        for (int q = 0; q < 8; ++q)
            p[q] = make_float4(acc[4 * q], acc[4 * q + 1], acc[4 * q + 2], acc[4 * q + 3]);
    }
}

// ---- layer-2 scatter: out[dst*32+o] += t[src*32+o], 32 lanes per edge ----
__global__ __launch_bounds__(256) void scatter_kernel(
    const int* __restrict__ ei, const uint16_t* __restrict__ tsrc,
    float* __restrict__ out) {
    long long gid = (long long)blockIdx.x * 256 + threadIdx.x;
    int e = (int)(gid >> 5);
    int o = (int)(gid & 31);
    if (e >= EE) return;
    int s = ei[e];
    int d = ei[EE + e];
    float v = bf2f(tsrc[(size_t)s * 32 + o]);
    atomicAdd(&out[(size_t)d * 32 + o], v);
}

extern "C" void kernel_launch(void* const* d_in, const int* in_sizes, int n_in,
                              void* d_out, int out_size, void* d_ws, size_t ws_size,
                              hipStream_t stream) {
    const float* x_a    = (const float*)d_in[0];
    const float* x_b    = (const float*)d_in[1];
    const int*   ei_ab  = (const int*)d_in[2];
    const int*   ei_ba  = (const int*)d_in[3];
    const int*   ei_aa  = (const int*)d_in[4];
    const float* Wrel1  = (const float*)d_in[5];
    const float* Wroot1 = (const float*)d_in[6];
    const float* b1     = (const float*)d_in[7];
    const float* Wrel2  = (const float*)d_in[8];
    const float* Wroot2 = (const float*)d_in[9];
    const float* b2     = (const float*)d_in[10];

    float* outa = (float*)d_out;                       // [NA,32]
    float* outb = (float*)d_out + (size_t)NA * 32;     // [NB,32]

    char* ws = (char*)d_ws;
    // layout: 3 scalar-agg arrays (fp32) + 3 transformed-feature arrays (bf16)
    float*    agg_ab = (float*)(ws);                   // NB
    float*    agg_ba = (float*)(ws + 2000000);         // NA
    float*    agg_aa = (float*)(ws + 4000000);         // NA
    uint16_t* ta0    = (uint16_t*)(ws + 6000000);              // NA*32
    uint16_t* ta2    = (uint16_t*)(ws + 6000000 + 32000000);   // NA*32
    uint16_t* tb1    = (uint16_t*)(ws + 6000000 + 64000000);   // NB*32
    if (ws_size < 102000000) return;  // need 102 MB scratch

    hipMemsetAsync(ws, 0, 6000000, stream);

    dim3 blk(256);
    int egrid = (EE + 255) / 256;
    edge_scalar_agg<<<egrid, blk, 0, stream>>>(ei_ab, x_a, agg_ab);
    edge_scalar_agg<<<egrid, blk, 0, stream>>>(ei_ba, x_b, agg_ba);
    edge_scalar_agg<<<egrid, blk, 0, stream>>>(ei_aa, x_a, agg_aa);

    int ngrid = (NA + 255) / 256;
    node_a_kernel<<<ngrid, blk, 0, stream>>>(x_a, agg_ba, agg_aa, Wrel1, Wroot1,
                                             b1, Wrel2, Wroot2, b2, ta0, ta2, outa);
    node_b_kernel<<<ngrid, blk, 0, stream>>>(x_b, agg_ab, Wrel1, Wroot1, b1,
                                             Wrel2, Wroot2, b2, tb1, outb);

    long long sthreads = (long long)EE * 32;
    int sgrid = (int)((sthreads + 255) / 256);
    scatter_kernel<<<sgrid, blk, 0, stream>>>(ei_ab, ta0, outb);
    scatter_kernel<<<sgrid, blk, 0, stream>>>(ei_ba, tb1, outa);
    scatter_kernel<<<sgrid, blk, 0, stream>>>(ei_aa, ta2, outa);
}

// Round 2
// 855.976 us; speedup vs baseline: 1.0327x; 1.0327x over previous
//
#include <hip/hip_runtime.h>
#include <hip/hip_bf16.h>
#include <stdint.h>

#define NA 500000
#define NB 500000
#define EE 1000000

__device__ __forceinline__ uint32_t f2bf(float f) {
    uint32_t b = __builtin_bit_cast(uint32_t, f);
    return (b + 0x7FFFu + ((b >> 16) & 1u)) >> 16;  // RNE
}
__device__ __forceinline__ float bf2f(uint16_t u) {
    uint32_t b = ((uint32_t)u) << 16;
    return __builtin_bit_cast(float, b);
}

// ---- layer-1 scalar aggregation, all 3 edge types fused ----
__global__ __launch_bounds__(256) void edge_agg_fused(
    const int* __restrict__ ei_ab, const int* __restrict__ ei_ba,
    const int* __restrict__ ei_aa,
    const float* __restrict__ xa, const float* __restrict__ xb,
    float* __restrict__ agg_ab, float* __restrict__ agg_ba,
    float* __restrict__ agg_aa) {
    int gid = blockIdx.x * 256 + threadIdx.x;
    if (gid < EE) {
        int e = gid;
        atomicAdd(&agg_ab[ei_ab[EE + e]], xa[ei_ab[e]]);
    } else if (gid < 2 * EE) {
        int e = gid - EE;
        atomicAdd(&agg_ba[ei_ba[EE + e]], xb[ei_ba[e]]);
    } else if (gid < 3 * EE) {
        int e = gid - 2 * EE;
        atomicAdd(&agg_aa[ei_aa[EE + e]], xa[ei_aa[e]]);
    }
}

// =================== node A ===================
// h = relu(sba*u + saa*v + x*w + c)  (64)
// ta0 = h@Wrel2[0] (bf16), ta2 = h@Wrel2[2] (bf16)
// outa = h@(Wroot2[1]+Wroot2[2]) + b2[1]+b2[2]  (fp32)
// All outputs staged in LDS -> lane-contiguous coalesced global stores.
__global__ __launch_bounds__(256) void node_a_kernel(
    const float* __restrict__ xa,
    const float* __restrict__ s_ba, const float* __restrict__ s_aa,
    const float* __restrict__ Wrel1, const float* __restrict__ Wroot1,
    const float* __restrict__ b1,
    const float* __restrict__ Wrel2, const float* __restrict__ Wroot2,
    const float* __restrict__ b2,
    uint16_t* __restrict__ ta0, uint16_t* __restrict__ ta2,
    float* __restrict__ outa) {
    __shared__ float uS[64], vS[64], wS[64], cS[64], bbS[32];
    __shared__ float W0[2048], W2[2048], WrS[2048];
    __shared__ uint32_t stageU[4352];  // 17 KB: bf16 stage 256*17, fp32 stage 128*33
    float* stageF = (float*)stageU;
    const int t = threadIdx.x;
    if (t < 64) {
        uS[t] = Wrel1[64 + t];
        vS[t] = Wrel1[128 + t];
        wS[t] = Wroot1[64 + t] + Wroot1[128 + t];
        cS[t] = b1[64 + t] + b1[128 + t];
    }
    if (t >= 64 && t < 96) bbS[t - 64] = b2[32 + (t - 64)] + b2[64 + (t - 64)];
    for (int i = t; i < 2048; i += 256) {
        W0[i]  = Wrel2[i];
        W2[i]  = Wrel2[4096 + i];
        WrS[i] = Wroot2[2048 + i] + Wroot2[4096 + i];
    }
    __syncthreads();

    const int blk = blockIdx.x;
    const int n = blk * 256 + t;
    const bool valid = (n < NA);
    const int validN = (NA - blk * 256) < 256 ? (NA - blk * 256) : 256;
    float sba = 0.f, saa = 0.f, x = 0.f;
    if (valid) { sba = s_ba[n]; saa = s_aa[n]; x = xa[n]; }

    // ---- pass 1: a0 (ta0) and a2 (ta2) ----
    float a0[32], a2[32];
#pragma unroll
    for (int o = 0; o < 32; ++o) { a0[o] = 0.f; a2[o] = 0.f; }
#pragma unroll 2
    for (int j = 0; j < 64; ++j) {
        float hj = fmaxf(fmaf(sba, uS[j], fmaf(saa, vS[j], fmaf(x, wS[j], cS[j]))), 0.f);
        const float4* w0 = (const float4*)(&W0[j * 32]);
        const float4* w2 = (const float4*)(&W2[j * 32]);
#pragma unroll
        for (int q = 0; q < 8; ++q) {
            float4 v0 = w0[q], v2 = w2[q];
            a0[q * 4 + 0] = fmaf(hj, v0.x, a0[q * 4 + 0]);
            a0[q * 4 + 1] = fmaf(hj, v0.y, a0[q * 4 + 1]);
            a0[q * 4 + 2] = fmaf(hj, v0.z, a0[q * 4 + 2]);
            a0[q * 4 + 3] = fmaf(hj, v0.w, a0[q * 4 + 3]);
            a2[q * 4 + 0] = fmaf(hj, v2.x, a2[q * 4 + 0]);
            a2[q * 4 + 1] = fmaf(hj, v2.y, a2[q * 4 + 1]);
            a2[q * 4 + 2] = fmaf(hj, v2.z, a2[q * 4 + 2]);
            a2[q * 4 + 3] = fmaf(hj, v2.w, a2[q * 4 + 3]);
        }
    }

    // ---- stage + store ta0 ----
    if (valid) {
#pragma unroll
        for (int k = 0; k < 16; ++k)
            stageU[t * 17 + k] = f2bf(a0[2 * k]) | (f2bf(a0[2 * k + 1]) << 16);
    }
    __syncthreads();
#pragma unroll
    for (int it = 0; it < 4; ++it) {
        int idx4 = t + 256 * it;           // uint4 index within block chunk
        if (idx4 < validN * 4) {
            int node = idx4 >> 2, q = (idx4 & 3) * 4;
            uint4 v = make_uint4(stageU[node * 17 + q], stageU[node * 17 + q + 1],
                                 stageU[node * 17 + q + 2], stageU[node * 17 + q + 3]);
            ((uint4*)ta0)[(size_t)blk * 1024 + idx4] = v;
        }
    }
    __syncthreads();
    // ---- stage + store ta2 ----
    if (valid) {
#pragma unroll
        for (int k = 0; k < 16; ++k)
            stageU[t * 17 + k] = f2bf(a2[2 * k]) | (f2bf(a2[2 * k + 1]) << 16);
    }
    __syncthreads();
#pragma unroll
    for (int it = 0; it < 4; ++it) {
        int idx4 = t + 256 * it;
        if (idx4 < validN * 4) {
            int node = idx4 >> 2, q = (idx4 & 3) * 4;
            uint4 v = make_uint4(stageU[node * 17 + q], stageU[node * 17 + q + 1],
                                 stageU[node * 17 + q + 2], stageU[node * 17 + q + 3]);
            ((uint4*)ta2)[(size_t)blk * 1024 + idx4] = v;
        }
    }

    // ---- pass 2: aR (outa root part + bias) ----
    float aR[32];
#pragma unroll
    for (int o = 0; o < 32; ++o) aR[o] = bbS[o];
#pragma unroll 2
    for (int j = 0; j < 64; ++j) {
        float hj = fmaxf(fmaf(sba, uS[j], fmaf(saa, vS[j], fmaf(x, wS[j], cS[j]))), 0.f);
        const float4* wr = (const float4*)(&WrS[j * 32]);
#pragma unroll
        for (int q = 0; q < 8; ++q) {
            float4 wv = wr[q];
            aR[q * 4 + 0] = fmaf(hj, wv.x, aR[q * 4 + 0]);
            aR[q * 4 + 1] = fmaf(hj, wv.y, aR[q * 4 + 1]);
            aR[q * 4 + 2] = fmaf(hj, wv.z, aR[q * 4 + 2]);
            aR[q * 4 + 3] = fmaf(hj, wv.w, aR[q * 4 + 3]);
        }
    }
    // two half-passes of 128 nodes each (16.5 KB fp32 stage)
#pragma unroll 1
    for (int p = 0; p < 2; ++p) {
        __syncthreads();
        int l = t - p * 128;
        if (l >= 0 && l < 128 && valid) {
#pragma unroll
            for (int k = 0; k < 32; ++k) stageF[l * 33 + k] = aR[k];
        }
        __syncthreads();
        int remN = NA - blk * 256 - p * 128;
        int validNp = remN < 0 ? 0 : (remN > 128 ? 128 : remN);
#pragma unroll
        for (int it = 0; it < 4; ++it) {
            int idx4 = t + 256 * it;        // float4 index within half chunk
            if (idx4 < validNp * 8) {
                int node = idx4 >> 3, q = (idx4 & 7) * 4;
                float4 v = make_float4(stageF[node * 33 + q], stageF[node * 33 + q + 1],
                                       stageF[node * 33 + q + 2], stageF[node * 33 + q + 3]);
                ((float4*)outa)[(size_t)blk * 2048 + p * 1024 + idx4] = v;
            }
        }
    }
}

// =================== node B ===================
__global__ __launch_bounds__(256) void node_b_kernel(
    const float* __restrict__ xb, const float* __restrict__ s_ab,
    const float* __restrict__ Wrel1, const float* __restrict__ Wroot1,
    const float* __restrict__ b1,
    const float* __restrict__ Wrel2, const float* __restrict__ Wroot2,
    const float* __restrict__ b2,
    uint16_t* __restrict__ tb1, float* __restrict__ outb) {
    __shared__ float uS[64], wS[64], cS[64], bbS[32];
    __shared__ float W1[2048], WrS[2048];
    __shared__ uint32_t stageU[4352];
    float* stageF = (float*)stageU;
    const int t = threadIdx.x;
    if (t < 64) {
        uS[t] = Wrel1[t];
        wS[t] = Wroot1[t];
        cS[t] = b1[t];
    }
    if (t >= 64 && t < 96) bbS[t - 64] = b2[t - 64];
    for (int i = t; i < 2048; i += 256) {
        W1[i]  = Wrel2[2048 + i];
        WrS[i] = Wroot2[i];
    }
    __syncthreads();

    const int blk = blockIdx.x;
    const int n = blk * 256 + t;
    const bool valid = (n < NB);
    const int validN = (NB - blk * 256) < 256 ? (NB - blk * 256) : 256;
    float sab = 0.f, x = 0.f;
    if (valid) { sab = s_ab[n]; x = xb[n]; }

    float a1[32], aR[32];
#pragma unroll
    for (int o = 0; o < 32; ++o) { a1[o] = 0.f; aR[o] = bbS[o]; }
#pragma unroll 2
    for (int j = 0; j < 64; ++j) {
        float hj = fmaxf(fmaf(sab, uS[j], fmaf(x, wS[j], cS[j])), 0.f);
        const float4* w1 = (const float4*)(&W1[j * 32]);
        const float4* wr = (const float4*)(&WrS[j * 32]);
#pragma unroll
        for (int q = 0; q < 8; ++q) {
            float4 v1 = w1[q], vr = wr[q];
            a1[q * 4 + 0] = fmaf(hj, v1.x, a1[q * 4 + 0]);
            a1[q * 4 + 1] = fmaf(hj, v1.y, a1[q * 4 + 1]);
            a1[q * 4 + 2] = fmaf(hj, v1.z, a1[q * 4 + 2]);
            a1[q * 4 + 3] = fmaf(hj, v1.w, a1[q * 4 + 3]);
            aR[q * 4 + 0] = fmaf(hj, vr.x, aR[q * 4 + 0]);
            aR[q * 4 + 1] = fmaf(hj, vr.y, aR[q * 4 + 1]);
            aR[q * 4 + 2] = fmaf(hj, vr.z, aR[q * 4 + 2]);
            aR[q * 4 + 3] = fmaf(hj, vr.w, aR[q * 4 + 3]);
        }
    }

    // ---- stage + store tb1 (bf16) ----
    if (valid) {
#pragma unroll
        for (int k = 0; k < 16; ++k)
            stageU[t * 17 + k] = f2bf(a1[2 * k]) | (f2bf(a1[2 * k + 1]) << 16);
    }
    __syncthreads();
#pragma unroll
    for (int it = 0; it < 4; ++it) {
        int idx4 = t + 256 * it;
        if (idx4 < validN * 4) {
            int node = idx4 >> 2, q = (idx4 & 3) * 4;
            uint4 v = make_uint4(stageU[node * 17 + q], stageU[node * 17 + q + 1],
                                 stageU[node * 17 + q + 2], stageU[node * 17 + q + 3]);
            ((uint4*)tb1)[(size_t)blk * 1024 + idx4] = v;
        }
    }

    // ---- stage + store outb (fp32, two half-passes) ----
#pragma unroll 1
    for (int p = 0; p < 2; ++p) {
        __syncthreads();
        int l = t - p * 128;
        if (l >= 0 && l < 128 && valid) {
#pragma unroll
            for (int k = 0; k < 32; ++k) stageF[l * 33 + k] = aR[k];
        }
        __syncthreads();
        int remN = NB - blk * 256 - p * 128;
        int validNp = remN < 0 ? 0 : (remN > 128 ? 128 : remN);
#pragma unroll
        for (int it = 0; it < 4; ++it) {
            int idx4 = t + 256 * it;
            if (idx4 < validNp * 8) {
                int node = idx4 >> 3, q = (idx4 & 7) * 4;
                float4 v = make_float4(stageF[node * 33 + q], stageF[node * 33 + q + 1],
                                       stageF[node * 33 + q + 2], stageF[node * 33 + q + 3]);
                ((float4*)outb)[(size_t)blk * 2048 + p * 1024 + idx4] = v;
            }
        }
    }
}

// ---- layer-2 scatter, all 3 edge types fused; 32 lanes per edge ----
__global__ __launch_bounds__(256) void scatter_fused(
    const int* __restrict__ ei_ab, const int* __restrict__ ei_ba,
    const int* __restrict__ ei_aa,
    const uint16_t* __restrict__ ta0, const uint16_t* __restrict__ tb1,
    const uint16_t* __restrict__ ta2,
    float* __restrict__ outa, float* __restrict__ outb) {
    long long gid = (long long)blockIdx.x * 256 + threadIdx.x;
    int e3 = (int)(gid >> 5);
    int o = (int)(gid & 31);
    const int* ei;
    const uint16_t* src;
    float* dst;
    int e;
    if (e3 < EE) {
        ei = ei_ab; src = ta0; dst = outb; e = e3;
    } else if (e3 < 2 * EE) {
        ei = ei_ba; src = tb1; dst = outa; e = e3 - EE;
    } else {
        ei = ei_aa; src = ta2; dst = outa; e = e3 - 2 * EE;
    }
    int s = ei[e];
    int d = ei[EE + e];
    float v = bf2f(src[(size_t)s * 32 + o]);
    atomicAdd(&dst[(size_t)d * 32 + o], v);
}

extern "C" void kernel_launch(void* const* d_in, const int* in_sizes, int n_in,
                              void* d_out, int out_size, void* d_ws, size_t ws_size,
                              hipStream_t stream) {
    const float* x_a    = (const float*)d_in[0];
    const float* x_b    = (const float*)d_in[1];
    const int*   ei_ab  = (const int*)d_in[2];
    const int*   ei_ba  = (const int*)d_in[3];
    const int*   ei_aa  = (const int*)d_in[4];
    const float* Wrel1  = (const float*)d_in[5];
    const float* Wroot1 = (const float*)d_in[6];
    const float* b1     = (const float*)d_in[7];
    const float* Wrel2  = (const float*)d_in[8];
    const float* Wroot2 = (const float*)d_in[9];
    const float* b2     = (const float*)d_in[10];

    float* outa = (float*)d_out;                       // [NA,32]
    float* outb = (float*)d_out + (size_t)NA * 32;     // [NB,32]

    char* ws = (char*)d_ws;
    float*    agg_ab = (float*)(ws);                   // NB floats
    float*    agg_ba = (float*)(ws + 2000000);         // NA floats
    float*    agg_aa = (float*)(ws + 4000000);         // NA floats
    uint16_t* ta0    = (uint16_t*)(ws + 6000000);              // NA*32 bf16
    uint16_t* ta2    = (uint16_t*)(ws + 6000000 + 32000000);   // NA*32 bf16
    uint16_t* tb1    = (uint16_t*)(ws + 6000000 + 64000000);   // NB*32 bf16
    if (ws_size < 102000000) return;  // need 102 MB scratch

    hipMemsetAsync(ws, 0, 6000000, stream);

    dim3 blk(256);
    int egrid = (3 * EE + 255) / 256;
    edge_agg_fused<<<egrid, blk, 0, stream>>>(ei_ab, ei_ba, ei_aa, x_a, x_b,
                                              agg_ab, agg_ba, agg_aa);

    int ngrid = (NA + 255) / 256;
    node_a_kernel<<<ngrid, blk, 0, stream>>>(x_a, agg_ba, agg_aa, Wrel1, Wroot1,
                                             b1, Wrel2, Wroot2, b2, ta0, ta2, outa);
    node_b_kernel<<<ngrid, blk, 0, stream>>>(x_b, agg_ab, Wrel1, Wroot1, b1,
                                             Wrel2, Wroot2, b2, tb1, outb);

    long long sthreads = (long long)3 * EE * 32;
    int sgrid = (int)((sthreads + 255) / 256);   // 375000 exactly
    scatter_fused<<<sgrid, blk, 0, stream>>>(ei_ab, ei_ba, ei_aa, ta0, tb1, ta2,
                                             outa, outb);
}